// Round 3
// baseline (455.533 us; speedup 1.0000x reference)
//
#include <hip/hip_runtime.h>
#include <cstdint>

// ---------------------------------------------------------------------------
// JanusCrossAttention: B=2,S=2048, Q_DIM=KV_DIM=2048, H=16, D=128, KVH=4
// I/O fp32; internals bf16 MFMA, fp32 accumulate.
//   1. cvt q_stream -> bf16 sb ; transpose weights -> bf16 [N][K]
//   2. xq = sb @ wqT  (m97-style global_load_lds GEMM)
//   3. cvt kv_stream -> sb ; xkv = sb @ wkvT  (fused K|V, N=1024)
//   4. per-head RMSNorm xq, xk
//   5. repack K and V^T into MFMA-fragment-major tiles
//   6. flash attention: NO LDS, no barriers. K/V fragments are read straight
//      from L2 (1 MB per (b,kvh) group, pinned to one XCD via bid%8 decode).
//      Paired q-tiles {31-p,p} fused into one 33-iter loop for balance.
//      exp2 softmax + defer-max, setprio around MFMA.
//   7. out = ao @ woT (fp32 out)
// ---------------------------------------------------------------------------

using bf16 = __bf16;
using bf16x4 = __attribute__((ext_vector_type(4))) __bf16;
using bf16x8 = __attribute__((ext_vector_type(8))) __bf16;
using s16x4  = __attribute__((ext_vector_type(4))) short;
using f32x4  = __attribute__((ext_vector_type(4))) float;

#define SEQ 2048
#define NH 16
#define NKVH 4
#define HD 128

// 16x16x16 bf16 MFMA (K=16) — C layout of a prior 16x16 MFMA feeds B directly.
#if defined(__has_builtin)
#if __has_builtin(__builtin_amdgcn_mfma_f32_16x16x16bf16_1k)
#define HAVE_1K 1
#endif
#endif
__device__ __forceinline__ f32x4 mfma_16x16x16(bf16x4 a, bf16x4 b, f32x4 c) {
#ifdef HAVE_1K
    return __builtin_amdgcn_mfma_f32_16x16x16bf16_1k(
        __builtin_bit_cast(s16x4, a), __builtin_bit_cast(s16x4, b), c, 0, 0, 0);
#else
    f32x4 d;
    asm volatile("v_mfma_f32_16x16x16_bf16 %0, %1, %2, %3"
                 : "=v"(d) : "v"(a), "v"(b), "v"(c));
    return d;
#endif
}

// native exp2 (v_exp_f32)
__device__ __forceinline__ float fast_exp2(float x) {
#if defined(__has_builtin)
#if __has_builtin(__builtin_amdgcn_exp2f)
    return __builtin_amdgcn_exp2f(x);
#else
    return exp2f(x);
#endif
#else
    return exp2f(x);
#endif
}

// async global->LDS, 16B per lane. LDS dest must be wave-uniform base + lane*16.
__device__ __forceinline__ void load_lds16(const bf16* g, bf16* l) {
    __builtin_amdgcn_global_load_lds(
        (const __attribute__((address_space(1))) unsigned int*)g,
        (__attribute__((address_space(3))) unsigned int*)l, 16, 0, 0);
}

// ---------------------------------------------------------------------------
__global__ __launch_bounds__(256) void cvt_f32_bf16(const float* __restrict__ in,
                                                    bf16* __restrict__ out, int n8) {
    int i = blockIdx.x * 256 + threadIdx.x;
    if (i >= n8) return;
    const float4* p = (const float4*)in + (long)i * 2;
    float4 f0 = p[0], f1 = p[1];
    bf16x8 o = {(bf16)f0.x, (bf16)f0.y, (bf16)f0.z, (bf16)f0.w,
                (bf16)f1.x, (bf16)f1.y, (bf16)f1.z, (bf16)f1.w};
    *((bf16x8*)out + i) = o;
}

// 2D transpose + cast: in fp32 [R][C] -> out bf16 [C][R]
__global__ void transpose2d(const float* __restrict__ in, bf16* __restrict__ out,
                            int R, int C) {
    __shared__ bf16 tile[32][33];
    int x  = blockIdx.x * 32 + threadIdx.x;
    int y0 = blockIdx.y * 32 + threadIdx.y;
#pragma unroll
    for (int i = 0; i < 32; i += 8) {
        int y = y0 + i;
        if (y < R && x < C) tile[threadIdx.y + i][threadIdx.x] = (bf16)in[(long)y * C + x];
    }
    __syncthreads();
    int ox  = blockIdx.y * 32 + threadIdx.x;
    int oy0 = blockIdx.x * 32 + threadIdx.y;
#pragma unroll
    for (int i = 0; i < 32; i += 8) {
        int oy = oy0 + i;
        if (oy < C && ox < R) out[(long)oy * R + ox] = tile[threadIdx.x][threadIdx.y + i];
    }
}

// ---------------------------------------------------------------------------
// GEMM: C[M][N] = A[M][K] @ BT[N][K]^T, bf16 in, fp32 acc, CT out.
// m97 recipe: 128x128 tile, BK=32, global_load_lds width-16 staging.
template <typename CT>
__global__ __launch_bounds__(256) void gemm_bt(const bf16* __restrict__ A,
                                               const bf16* __restrict__ BT,
                                               CT* __restrict__ C,
                                               int M, int N, int K) {
    __shared__ bf16 As[128][32];
    __shared__ bf16 Bs[128][32];
    const int tid  = threadIdx.x;
    const int wave = tid >> 6, lane = tid & 63;
    const int m0 = blockIdx.y * 128, n0 = blockIdx.x * 128;
    const int wm = (wave >> 1) * 64, wn = (wave & 1) * 64;
    const int lrow = lane & 15, quad = lane >> 4;
    const int lko = quad * 8;

    const bf16* ga0 = A  + (long)(m0 + (tid >> 2)) * K + (tid & 3) * 8;
    const bf16* ga1 = ga0 + 64L * K;
    const bf16* gb0 = BT + (long)(n0 + (tid >> 2)) * K + (tid & 3) * 8;
    const bf16* gb1 = gb0 + 64L * K;
    bf16* la0 = &As[0][0] + tid * 8;
    bf16* la1 = la0 + 2048;
    bf16* lb0 = &Bs[0][0] + tid * 8;
    bf16* lb1 = lb0 + 2048;

    f32x4 acc[4][4] = {};

    for (int k0 = 0; k0 < K; k0 += 32) {
        load_lds16(ga0 + k0, la0);
        load_lds16(ga1 + k0, la1);
        load_lds16(gb0 + k0, lb0);
        load_lds16(gb1 + k0, lb1);
        __syncthreads();
        bf16x8 af[4], bfr[4];
#pragma unroll
        for (int i = 0; i < 4; ++i) af[i]  = *(const bf16x8*)(&As[wm + i * 16 + lrow][lko]);
#pragma unroll
        for (int j = 0; j < 4; ++j) bfr[j] = *(const bf16x8*)(&Bs[wn + j * 16 + lrow][lko]);
#pragma unroll
        for (int i = 0; i < 4; ++i)
#pragma unroll
            for (int j = 0; j < 4; ++j)
                acc[i][j] = __builtin_amdgcn_mfma_f32_16x16x32_bf16(af[i], bfr[j], acc[i][j], 0, 0, 0);
        __syncthreads();
    }
#pragma unroll
    for (int i = 0; i < 4; ++i) {
        int mrow0 = m0 + wm + i * 16 + quad * 4;
#pragma unroll
        for (int j = 0; j < 4; ++j) {
            int ncol = n0 + wn + j * 16 + lrow;
#pragma unroll
            for (int r = 0; r < 4; ++r)
                C[(long)(mrow0 + r) * N + ncol] = (CT)acc[i][j][r];
        }
    }
}

// ---------------------------------------------------------------------------
// Per-head RMSNorm, wave per 128-vector, in-place.
__global__ __launch_bounds__(256) void rmsnorm_head(bf16* __restrict__ X,
                                                    const float* __restrict__ W,
                                                    int nvec, int lhpr, int stride) {
    int v = blockIdx.x * 4 + (threadIdx.x >> 6);
    int lane = threadIdx.x & 63;
    if (v >= nvec) return;
    int row = v >> lhpr, head = v & ((1 << lhpr) - 1);
    bf16* x = X + (long)row * stride + head * HD;
    float fa = (float)x[lane * 2], fb = (float)x[lane * 2 + 1];
    float ss = fa * fa + fb * fb;
#pragma unroll
    for (int off = 1; off < 64; off <<= 1) ss += __shfl_xor(ss, off, 64);
    float r = rsqrtf(ss * (1.0f / 128.0f) + 1e-5f);
    x[lane * 2]     = (bf16)(fa * r * W[lane * 2]);
    x[lane * 2 + 1] = (bf16)(fb * r * W[lane * 2 + 1]);
}

// ---------------------------------------------------------------------------
// Repack K (post-RMSNorm) into fragment-major tiles:
// kf[(b*4+kvh)*32 + kt][nt(4)][ks(4)][lane(64)][8] with
//   key = kt*64 + nt*16 + (lane&15), d = ks*32 + (lane>>4)*8 + j.
// This is exactly the 16x16x32 A-operand order -> attn reads at lane*16B.
__global__ __launch_bounds__(256) void repack_k(const bf16* __restrict__ xkv,
                                                bf16* __restrict__ kf) {
    int kt = blockIdx.x, kvh = blockIdx.y, b = blockIdx.z;
    int tid = threadIdx.x, lane = tid & 63, ks = tid >> 6;
    int lrow = lane & 15, quad = lane >> 4;
    const bf16* src = xkv + ((long)b * SEQ + kt * 64) * 1024 + kvh * HD;
    bf16* dst = kf + ((long)((b * NKVH + kvh) * 32 + kt)) * 8192;
#pragma unroll
    for (int nt = 0; nt < 4; ++nt) {
        bf16x8 v = *(const bf16x8*)(src + (long)(nt * 16 + lrow) * 1024 + ks * 32 + quad * 8);
        *(bf16x8*)(dst + ((nt * 4 + ks) * 64 + lane) * 8) = v;
    }
}

// Repack V^T into fragment-major tiles:
// vf[(b*4+kvh)*32 + kt][nt(4)][dt(8)][lane(64)][4] with
//   d = dt*16 + (lane&15), key = kt*64 + nt*16 + (lane>>4)*4 + j.
// This is the 16x16x16 A-operand order. Transpose via LDS.
__global__ __launch_bounds__(256) void repack_v(const bf16* __restrict__ xkv,
                                                bf16* __restrict__ vf) {
    __shared__ bf16 Vls[64][136];
    int kt = blockIdx.x, kvh = blockIdx.y, b = blockIdx.z;
    int tid = threadIdx.x;
    const bf16* src = xkv + ((long)b * SEQ + kt * 64) * 1024 + 512 + kvh * HD;
#pragma unroll
    for (int p = 0; p < 4; ++p) {
        int c = p * 256 + tid;
        int r = c >> 4, dc = (c & 15) * 8;
        *(uint4*)(&Vls[r][dc]) = *(const uint4*)(src + (long)r * 1024 + dc);
    }
    __syncthreads();
    int lane = tid & 63, w = tid >> 6, lrow = lane & 15, quad = lane >> 4;
    bf16* dst = vf + ((long)((b * NKVH + kvh) * 32 + kt)) * 8192;
#pragma unroll
    for (int nt = 0; nt < 4; ++nt)
#pragma unroll
        for (int dtl = 0; dtl < 2; ++dtl) {
            int dt = w * 2 + dtl;
            bf16x4 v = {Vls[nt * 16 + quad * 4 + 0][dt * 16 + lrow],
                        Vls[nt * 16 + quad * 4 + 1][dt * 16 + lrow],
                        Vls[nt * 16 + quad * 4 + 2][dt * 16 + lrow],
                        Vls[nt * 16 + quad * 4 + 3][dt * 16 + lrow]};
            *(bf16x4*)(dst + ((nt * 8 + dt) * 64 + lane) * 4) = v;
        }
}

// ---------------------------------------------------------------------------
// Flash attention, S^T register-P scheme, fragment-major K/V read DIRECTLY
// from global (L2). No LDS, no barriers — waves fully independent.
//
// Grid 512 1-D. Decode: (b,kvh) = bid&7 — there are exactly 8 (b,kvh) groups
// and 8 XCDs; with the HW's bid%8 XCD round-robin every XCD serves ONE group,
// whose K/V fragments (kf+vf = 1 MB) + Q slice (2 MB) are L2-resident. That
// kills both the R2 re-fetch (54 MB) and the per-iteration HBM-latency drain.
// R2 lesson: LDS staging of L2-fit data was pure overhead (vmcnt(0) drain at
// the barrier exposed full memory latency every iteration; MFMA-busy was
// already at the ~21 µs floor).
//
// Block p fuses q-tiles {31-p, p} into one 33-iteration loop — every block
// does exactly 33 iterations under ANY placement.
// Softmax in exp2 domain + defer-max (T13); s_setprio(1) around MFMA (T5).
__global__ __launch_bounds__(256, 2) void attn_kernel(const bf16* __restrict__ Q,
                                                      const bf16* __restrict__ KF,
                                                      const bf16* __restrict__ VF,
                                                      bf16* __restrict__ O) {
    const int tid = threadIdx.x, wave = tid >> 6, lane = tid & 63;
    const int bid = blockIdx.x;
    const int grp = bid & 7;                  // -> XCD via bid%8 round-robin
    const int b = grp >> 2, kvh = grp & 3;
    const int slot = bid >> 3;                // 0..63
    const int pr = slot & 15;
    const int h = kvh * 4 + (slot >> 4);
    const int lrow = lane & 15, quad = lane >> 4;
    const float scl2 = 0.12751744f;     // (1/sqrt(128)) * log2(e)
    const float THR = 62.7f;            // ~8 ln-units in raw-score domain

    const int qt1 = 31 - pr, qt2 = pr;
    const int nkb1 = qt1 + 1;            // 17..32
    const int TOTAL = 33;                // nkb1 + (qt2+1)

    const bf16* kfb = KF + ((long)(b * NKVH + kvh) * 32) * 8192;
    const bf16* vfb = VF + ((long)(b * NKVH + kvh) * 32) * 8192;

    // Q fragments for both tiles, loaded up front.
    const int myq1 = qt1 * 64 + wave * 16 + lrow;
    const int myq2 = qt2 * 64 + wave * 16 + lrow;
    const bf16* qrow1 = Q + ((long)(b * SEQ + myq1)) * (NH * HD) + h * HD;
    const bf16* qrow2 = Q + ((long)(b * SEQ + myq2)) * (NH * HD) + h * HD;
    bf16x8 bqw[4], bq2[4];
#pragma unroll
    for (int ks = 0; ks < 4; ++ks) {
        bqw[ks] = *(const bf16x8*)(qrow1 + ks * 32 + quad * 8);
        bq2[ks] = *(const bf16x8*)(qrow2 + ks * 32 + quad * 8);
    }

    float m_i = -__builtin_inff(), l_i = 0.f;
    f32x4 oT[8] = {};   // out^T: d = dt*16 + quad*4 + r, q = lane&15
    int myq = myq1;

    // epilogue writer (8B stores per dt)
    auto epilogue = [&](int qrow) {
        float inv_l = 1.0f / l_i;
        bf16* obase = O + ((long)(b * SEQ + qrow)) * (NH * HD) + h * HD;
#pragma unroll
        for (int dt = 0; dt < 8; ++dt) {
            bf16x4 o = {(bf16)(oT[dt][0] * inv_l), (bf16)(oT[dt][1] * inv_l),
                        (bf16)(oT[dt][2] * inv_l), (bf16)(oT[dt][3] * inv_l)};
            *(bf16x4*)(obase + dt * 16 + quad * 4) = o;
        }
    };

#pragma unroll 1
    for (int i = 0; i < TOTAL; ++i) {
        const int kb = (i < nkb1) ? i : i - nkb1;
        const bool diag = (i == nkb1 - 1) || (i == TOTAL - 1);
        const bf16* ktb = kfb + (long)kb * 8192;
        const bf16* vtb = vfb + (long)kb * 8192;

        // K fragments straight from L2: 16 x 16B/lane, lane-coalesced.
        bf16x8 ak[4][4];
#pragma unroll
        for (int nt = 0; nt < 4; ++nt)
#pragma unroll
            for (int ks = 0; ks < 4; ++ks)
                ak[nt][ks] = *(const bf16x8*)(ktb + ((nt * 4 + ks) * 64 + lane) * 8);

        // S^T raw scores: key-tile nt covers keys kb*64+nt*16+quad*4+{0..3}, q=lrow
        f32x4 st[4];
        __builtin_amdgcn_s_setprio(1);
#pragma unroll
        for (int nt = 0; nt < 4; ++nt) {
            f32x4 acc = {};
#pragma unroll
            for (int ks = 0; ks < 4; ++ks)
                acc = __builtin_amdgcn_mfma_f32_16x16x32_bf16(ak[nt][ks], bqw[ks], acc, 0, 0, 0);
            st[nt] = acc;
        }
        __builtin_amdgcn_s_setprio(0);

        // V fragments from L2: 32 x 8B/lane, lane-coalesced. Issued here so
        // the softmax below covers their ~200cy L2 latency.
        bf16x4 av[4][8];
#pragma unroll
        for (int nt = 0; nt < 4; ++nt)
#pragma unroll
            for (int dt = 0; dt < 8; ++dt)
                av[nt][dt] = *(const bf16x4*)(vtb + ((nt * 8 + dt) * 64 + lane) * 4);

        if (diag) {
#pragma unroll
            for (int nt = 0; nt < 4; ++nt) {
                int kp0 = kb * 64 + nt * 16 + quad * 4;
#pragma unroll
                for (int r = 0; r < 4; ++r)
                    if (kp0 + r > myq) st[nt][r] = -__builtin_inff();
            }
        }

        // per-lane online softmax (lane owns one q row; keys spread over quads)
        float mx = st[0][0];
#pragma unroll
        for (int nt = 0; nt < 4; ++nt)
#pragma unroll
            for (int r = 0; r < 4; ++r) mx = fmaxf(mx, st[nt][r]);
        mx = fmaxf(mx, __shfl_xor(mx, 16, 64));
        mx = fmaxf(mx, __shfl_xor(mx, 32, 64));

        // defer-max: only rescale when some row's max grew past THR
        if (!__all(mx - m_i <= THR)) {
            float mnew = fmaxf(m_i, mx);
            float alpha = fast_exp2((m_i - mnew) * scl2);
            l_i *= alpha;
#pragma unroll
            for (int dt = 0; dt < 8; ++dt)
#pragma unroll
                for (int r = 0; r < 4; ++r) oT[dt][r] *= alpha;
            m_i = mnew;
        }
        float rs = 0.f;
#pragma unroll
        for (int nt = 0; nt < 4; ++nt)
#pragma unroll
            for (int r = 0; r < 4; ++r) {
                float p = fast_exp2((st[nt][r] - m_i) * scl2);
                st[nt][r] = p;
                rs += p;
            }
        rs += __shfl_xor(rs, 16, 64);
        rs += __shfl_xor(rs, 32, 64);
        l_i += rs;

        // P fragments (16x16x16 B-operand): B[n=q=lane&15][k=key=quad*4+j]
        bf16x4 pf[4];
#pragma unroll
        for (int nt = 0; nt < 4; ++nt) {
            bf16x4 tt = {(bf16)st[nt][0], (bf16)st[nt][1],
                         (bf16)st[nt][2], (bf16)st[nt][3]};
            pf[nt] = tt;
        }

        // PV: out^T += V^T · P^T, key-steps of 16
        __builtin_amdgcn_s_setprio(1);
#pragma unroll
        for (int nt = 0; nt < 4; ++nt)
#pragma unroll
            for (int dt = 0; dt < 8; ++dt)
                oT[dt] = mfma_16x16x16(av[nt][dt], pf[nt], oT[dt]);
        __builtin_amdgcn_s_setprio(0);

        // seam: finish tile 1, reset softmax state, switch Q fragments
        if (i == nkb1 - 1) {
            epilogue(myq1);
            m_i = -__builtin_inff();
            l_i = 0.f;
#pragma unroll
            for (int dt = 0; dt < 8; ++dt)
#pragma unroll
                for (int r = 0; r < 4; ++r) oT[dt][r] = 0.f;
            myq = myq2;
#pragma unroll
            for (int ks = 0; ks < 4; ++ks) bqw[ks] = bq2[ks];
        }
    }

    epilogue(myq2);
}

// ---------------------------------------------------------------------------
extern "C" void kernel_launch(void* const* d_in, const int* in_sizes, int n_in,
                              void* d_out, int out_size, void* d_ws, size_t ws_size,
                              hipStream_t stream) {
    const float* q_stream  = (const float*)d_in[0];
    const float* kv_stream = (const float*)d_in[1];
    const float* wq  = (const float*)d_in[2];
    const float* wk  = (const float*)d_in[3];
    const float* wv  = (const float*)d_in[4];
    const float* wo  = (const float*)d_in[5];
    const float* qnw = (const float*)d_in[6];
    const float* knw = (const float*)d_in[7];
    float* out = (float*)d_out;

    // workspace (bf16 elems), total 30M elems = 60MB
    bf16* ws   = (bf16*)d_ws;
    bf16* sb   = ws;                        // 8M: stream buf, later attn out
    bf16* wqT  = ws + 8L * 1024 * 1024;     // 4M: wq^T, later wo^T
    bf16* wkvT = wqT + 4L * 1024 * 1024;    // 2M: [wk^T ; wv^T] = [1024][2048]
    bf16* xq   = wkvT + 2L * 1024 * 1024;   // 8M: [4096][2048]
    bf16* xkv  = xq + 8L * 1024 * 1024;     // 4M: [4096][1024] = [K | V]
    bf16* kf   = xkv + 4L * 1024 * 1024;    // 2M: K fragment-major
    bf16* vf   = kf + 2L * 1024 * 1024;     // 2M: V^T fragment-major

    dim3 tb(32, 8);
    cvt_f32_bf16<<<4096, 256, 0, stream>>>(q_stream, sb, 1048576);
    transpose2d<<<dim3(64, 64), tb, 0, stream>>>(wq, wqT, 2048, 2048);
    transpose2d<<<dim3(16, 64), tb, 0, stream>>>(wk, wkvT, 2048, 512);
    transpose2d<<<dim3(16, 64), tb, 0, stream>>>(wv, wkvT + 512L * 2048, 2048, 512);
    gemm_bt<bf16><<<dim3(16, 32), 256, 0, stream>>>(sb, wqT, xq, 4096, 2048, 2048);
    cvt_f32_bf16<<<4096, 256, 0, stream>>>(kv_stream, sb, 1048576);
    transpose2d<<<dim3(64, 64), tb, 0, stream>>>(wo, wqT, 2048, 2048);
    gemm_bt<bf16><<<dim3(8, 32), 256, 0, stream>>>(sb, wkvT, xkv, 4096, 1024, 2048);
    rmsnorm_head<<<(4096 * 16) / 4, 256, 0, stream>>>(xq, qnw, 4096 * 16, 4, 2048);
    rmsnorm_head<<<(4096 * 4) / 4, 256, 0, stream>>>(xkv, knw, 4096 * 4, 2, 1024);
    repack_k<<<dim3(32, 4, 2), 256, 0, stream>>>(xkv, kf);
    repack_v<<<dim3(32, 4, 2), 256, 0, stream>>>(xkv, vf);
    attn_kernel<<<dim3(512), 256, 0, stream>>>(xq, kf, vf, sb);
    gemm_bt<float><<<dim3(16, 32), 256, 0, stream>>>(sb, wqT, out, 4096, 2048, 2048);

    (void)in_sizes; (void)n_in; (void)out_size; (void)ws_size;
}

// Round 4
// 411.956 us; speedup vs baseline: 1.1058x; 1.1058x over previous
//
#include <hip/hip_runtime.h>
#include <cstdint>

// ---------------------------------------------------------------------------
// JanusCrossAttention: B=2,S=2048, Q_DIM=KV_DIM=2048, H=16, D=128, KVH=4
// I/O fp32; internals bf16 MFMA, fp32 accumulate.
//   1. cvt q_stream -> bf16 sb ; transpose weights -> bf16 [N][K]
//   2. xq = sb @ wqT  (m97-style global_load_lds GEMM)
//   3. cvt kv_stream -> sb ; xkv = sb @ wkvT  (fused K|V, N=1024)
//   4. per-head RMSNorm xq, xk
//   5. repack K and V^T into MFMA-fragment-major tiles
//   6. flash attention: R2's double-buffered LDS staging (amortizes K/V reads
//      across the block's 4 waves: 32 KB/blk-iter from L2, not 128 KB) +
//      R3's (b,kvh)=bid&7 XCD pinning (1 MB K/V + 2 MB Q resident per XCD's
//      L2 -> staging loads are L2-hits, fully covered by the compute phase
//      before the barrier's vmcnt drain). Paired q-tiles {31-p,p} fused into
//      one 33-iter loop for placement-independent balance. exp2 softmax +
//      defer-max, setprio around MFMA.
//   7. out = ao @ woT (fp32 out)
// ---------------------------------------------------------------------------

using bf16 = __bf16;
using bf16x4 = __attribute__((ext_vector_type(4))) __bf16;
using bf16x8 = __attribute__((ext_vector_type(8))) __bf16;
using s16x4  = __attribute__((ext_vector_type(4))) short;
using f32x4  = __attribute__((ext_vector_type(4))) float;

#define SEQ 2048
#define NH 16
#define NKVH 4
#define HD 128

// 16x16x16 bf16 MFMA (K=16) — C layout of a prior 16x16 MFMA feeds B directly.
#if defined(__has_builtin)
#if __has_builtin(__builtin_amdgcn_mfma_f32_16x16x16bf16_1k)
#define HAVE_1K 1
#endif
#endif
__device__ __forceinline__ f32x4 mfma_16x16x16(bf16x4 a, bf16x4 b, f32x4 c) {
#ifdef HAVE_1K
    return __builtin_amdgcn_mfma_f32_16x16x16bf16_1k(
        __builtin_bit_cast(s16x4, a), __builtin_bit_cast(s16x4, b), c, 0, 0, 0);
#else
    f32x4 d;
    asm volatile("v_mfma_f32_16x16x16_bf16 %0, %1, %2, %3"
                 : "=v"(d) : "v"(a), "v"(b), "v"(c));
    return d;
#endif
}

// native exp2 (v_exp_f32)
__device__ __forceinline__ float fast_exp2(float x) {
#if defined(__has_builtin)
#if __has_builtin(__builtin_amdgcn_exp2f)
    return __builtin_amdgcn_exp2f(x);
#else
    return exp2f(x);
#endif
#else
    return exp2f(x);
#endif
}

// async global->LDS, 16B per lane. LDS dest must be wave-uniform base + lane*16.
__device__ __forceinline__ void load_lds16(const bf16* g, bf16* l) {
    __builtin_amdgcn_global_load_lds(
        (const __attribute__((address_space(1))) unsigned int*)g,
        (__attribute__((address_space(3))) unsigned int*)l, 16, 0, 0);
}

// ---------------------------------------------------------------------------
__global__ __launch_bounds__(256) void cvt_f32_bf16(const float* __restrict__ in,
                                                    bf16* __restrict__ out, int n8) {
    int i = blockIdx.x * 256 + threadIdx.x;
    if (i >= n8) return;
    const float4* p = (const float4*)in + (long)i * 2;
    float4 f0 = p[0], f1 = p[1];
    bf16x8 o = {(bf16)f0.x, (bf16)f0.y, (bf16)f0.z, (bf16)f0.w,
                (bf16)f1.x, (bf16)f1.y, (bf16)f1.z, (bf16)f1.w};
    *((bf16x8*)out + i) = o;
}

// 2D transpose + cast: in fp32 [R][C] -> out bf16 [C][R]
__global__ void transpose2d(const float* __restrict__ in, bf16* __restrict__ out,
                            int R, int C) {
    __shared__ bf16 tile[32][33];
    int x  = blockIdx.x * 32 + threadIdx.x;
    int y0 = blockIdx.y * 32 + threadIdx.y;
#pragma unroll
    for (int i = 0; i < 32; i += 8) {
        int y = y0 + i;
        if (y < R && x < C) tile[threadIdx.y + i][threadIdx.x] = (bf16)in[(long)y * C + x];
    }
    __syncthreads();
    int ox  = blockIdx.y * 32 + threadIdx.x;
    int oy0 = blockIdx.x * 32 + threadIdx.y;
#pragma unroll
    for (int i = 0; i < 32; i += 8) {
        int oy = oy0 + i;
        if (oy < C && ox < R) out[(long)oy * R + ox] = tile[threadIdx.x][threadIdx.y + i];
    }
}

// ---------------------------------------------------------------------------
// GEMM: C[M][N] = A[M][K] @ BT[N][K]^T, bf16 in, fp32 acc, CT out.
// m97 recipe: 128x128 tile, BK=32, global_load_lds width-16 staging.
template <typename CT>
__global__ __launch_bounds__(256) void gemm_bt(const bf16* __restrict__ A,
                                               const bf16* __restrict__ BT,
                                               CT* __restrict__ C,
                                               int M, int N, int K) {
    __shared__ bf16 As[128][32];
    __shared__ bf16 Bs[128][32];
    const int tid  = threadIdx.x;
    const int wave = tid >> 6, lane = tid & 63;
    const int m0 = blockIdx.y * 128, n0 = blockIdx.x * 128;
    const int wm = (wave >> 1) * 64, wn = (wave & 1) * 64;
    const int lrow = lane & 15, quad = lane >> 4;
    const int lko = quad * 8;

    const bf16* ga0 = A  + (long)(m0 + (tid >> 2)) * K + (tid & 3) * 8;
    const bf16* ga1 = ga0 + 64L * K;
    const bf16* gb0 = BT + (long)(n0 + (tid >> 2)) * K + (tid & 3) * 8;
    const bf16* gb1 = gb0 + 64L * K;
    bf16* la0 = &As[0][0] + tid * 8;
    bf16* la1 = la0 + 2048;
    bf16* lb0 = &Bs[0][0] + tid * 8;
    bf16* lb1 = lb0 + 2048;

    f32x4 acc[4][4] = {};

    for (int k0 = 0; k0 < K; k0 += 32) {
        load_lds16(ga0 + k0, la0);
        load_lds16(ga1 + k0, la1);
        load_lds16(gb0 + k0, lb0);
        load_lds16(gb1 + k0, lb1);
        __syncthreads();
        bf16x8 af[4], bfr[4];
#pragma unroll
        for (int i = 0; i < 4; ++i) af[i]  = *(const bf16x8*)(&As[wm + i * 16 + lrow][lko]);
#pragma unroll
        for (int j = 0; j < 4; ++j) bfr[j] = *(const bf16x8*)(&Bs[wn + j * 16 + lrow][lko]);
#pragma unroll
        for (int i = 0; i < 4; ++i)
#pragma unroll
            for (int j = 0; j < 4; ++j)
                acc[i][j] = __builtin_amdgcn_mfma_f32_16x16x32_bf16(af[i], bfr[j], acc[i][j], 0, 0, 0);
        __syncthreads();
    }
#pragma unroll
    for (int i = 0; i < 4; ++i) {
        int mrow0 = m0 + wm + i * 16 + quad * 4;
#pragma unroll
        for (int j = 0; j < 4; ++j) {
            int ncol = n0 + wn + j * 16 + lrow;
#pragma unroll
            for (int r = 0; r < 4; ++r)
                C[(long)(mrow0 + r) * N + ncol] = (CT)acc[i][j][r];
        }
    }
}

// ---------------------------------------------------------------------------
// Per-head RMSNorm, wave per 128-vector, in-place.
__global__ __launch_bounds__(256) void rmsnorm_head(bf16* __restrict__ X,
                                                    const float* __restrict__ W,
                                                    int nvec, int lhpr, int stride) {
    int v = blockIdx.x * 4 + (threadIdx.x >> 6);
    int lane = threadIdx.x & 63;
    if (v >= nvec) return;
    int row = v >> lhpr, head = v & ((1 << lhpr) - 1);
    bf16* x = X + (long)row * stride + head * HD;
    float fa = (float)x[lane * 2], fb = (float)x[lane * 2 + 1];
    float ss = fa * fa + fb * fb;
#pragma unroll
    for (int off = 1; off < 64; off <<= 1) ss += __shfl_xor(ss, off, 64);
    float r = rsqrtf(ss * (1.0f / 128.0f) + 1e-5f);
    x[lane * 2]     = (bf16)(fa * r * W[lane * 2]);
    x[lane * 2 + 1] = (bf16)(fb * r * W[lane * 2 + 1]);
}

// ---------------------------------------------------------------------------
// Repack K (post-RMSNorm) into fragment-major tiles:
// kf[(b*4+kvh)*32 + kt][nt(4)][ks(4)][lane(64)][8] with
//   key = kt*64 + nt*16 + (lane&15), d = ks*32 + (lane>>4)*8 + j.
// This is exactly the 16x16x32 A-operand order -> attn LDS reads at lane*16.
__global__ __launch_bounds__(256) void repack_k(const bf16* __restrict__ xkv,
                                                bf16* __restrict__ kf) {
    int kt = blockIdx.x, kvh = blockIdx.y, b = blockIdx.z;
    int tid = threadIdx.x, lane = tid & 63, ks = tid >> 6;
    int lrow = lane & 15, quad = lane >> 4;
    const bf16* src = xkv + ((long)b * SEQ + kt * 64) * 1024 + kvh * HD;
    bf16* dst = kf + ((long)((b * NKVH + kvh) * 32 + kt)) * 8192;
#pragma unroll
    for (int nt = 0; nt < 4; ++nt) {
        bf16x8 v = *(const bf16x8*)(src + (long)(nt * 16 + lrow) * 1024 + ks * 32 + quad * 8);
        *(bf16x8*)(dst + ((nt * 4 + ks) * 64 + lane) * 8) = v;
    }
}

// Repack V^T into fragment-major tiles:
// vf[(b*4+kvh)*32 + kt][nt(4)][dt(8)][lane(64)][4] with
//   d = dt*16 + (lane&15), key = kt*64 + nt*16 + (lane>>4)*4 + j.
// This is the 16x16x16 A-operand order. Transpose via LDS.
__global__ __launch_bounds__(256) void repack_v(const bf16* __restrict__ xkv,
                                                bf16* __restrict__ vf) {
    __shared__ bf16 Vls[64][136];
    int kt = blockIdx.x, kvh = blockIdx.y, b = blockIdx.z;
    int tid = threadIdx.x;
    const bf16* src = xkv + ((long)b * SEQ + kt * 64) * 1024 + 512 + kvh * HD;
#pragma unroll
    for (int p = 0; p < 4; ++p) {
        int c = p * 256 + tid;
        int r = c >> 4, dc = (c & 15) * 8;
        *(uint4*)(&Vls[r][dc]) = *(const uint4*)(src + (long)r * 1024 + dc);
    }
    __syncthreads();
    int lane = tid & 63, w = tid >> 6, lrow = lane & 15, quad = lane >> 4;
    bf16* dst = vf + ((long)((b * NKVH + kvh) * 32 + kt)) * 8192;
#pragma unroll
    for (int nt = 0; nt < 4; ++nt)
#pragma unroll
        for (int dtl = 0; dtl < 2; ++dtl) {
            int dt = w * 2 + dtl;
            bf16x4 v = {Vls[nt * 16 + quad * 4 + 0][dt * 16 + lrow],
                        Vls[nt * 16 + quad * 4 + 1][dt * 16 + lrow],
                        Vls[nt * 16 + quad * 4 + 2][dt * 16 + lrow],
                        Vls[nt * 16 + quad * 4 + 3][dt * 16 + lrow]};
            *(bf16x4*)(dst + ((nt * 8 + dt) * 64 + lane) * 4) = v;
        }
}

// ---------------------------------------------------------------------------
// Flash attention: R2 double-buffered-LDS structure + R3 XCD pinning.
//
// Grid 512 1-D. Decode: (b,kvh) = bid&7 — 8 groups onto 8 XCDs via the HW's
// bid%8 round-robin. Each XCD then serves 64 blocks that share ONE group's
// K/V fragments (1 MB) + Q slice (2 MB): L2-resident after first touch
// (R3 proved it: FETCH 54->12 MB). Staging loads are L2 hits (~200-400 cyc),
// fully covered by the compute phase before the barrier's vmcnt drain.
// LDS staging amortizes K/V across the block's 4 waves (32 KB/blk-iter from
// L2, not 128 KB — R3's direct-read was L2-BW/latency-bound at 124 µs).
//
// Block p fuses q-tiles {31-p, p} into one 33-iteration loop — every block
// does exactly 33 iterations under ANY placement.
// Softmax in exp2 domain + defer-max (T13); s_setprio(1) around MFMA (T5).
__global__ __launch_bounds__(256, 2) void attn_kernel(const bf16* __restrict__ Q,
                                                      const bf16* __restrict__ KF,
                                                      const bf16* __restrict__ VF,
                                                      bf16* __restrict__ O) {
    __shared__ bf16 Kf[2][4][4][512];   // [buf][nt][ks][lane*8] — 32 KB
    __shared__ bf16 Vf[2][4][8][256];   // [buf][nt][dt][lane*4] — 32 KB
    const int tid = threadIdx.x, wave = tid >> 6, lane = tid & 63;
    const int bid = blockIdx.x;
    const int grp = bid & 7;                  // -> XCD via bid%8 round-robin
    const int b = grp >> 2, kvh = grp & 3;
    const int slot = bid >> 3;                // 0..63
    const int pr = slot & 15;
    const int h = kvh * 4 + (slot >> 4);
    const int lrow = lane & 15, quad = lane >> 4;
    const float scl2 = 0.12751744f;     // (1/sqrt(128)) * log2(e)
    const float THR = 62.7f;            // ~8 ln-units in raw-score domain

    const int qt1 = 31 - pr, qt2 = pr;
    const int nkb1 = qt1 + 1;            // 17..32
    const int TOTAL = 33;                // nkb1 + (qt2+1)

    const bf16* kfb = KF + ((long)(b * NKVH + kvh) * 32) * 8192;
    const bf16* vfb = VF + ((long)(b * NKVH + kvh) * 32) * 8192;

    // Q fragments for both tiles, loaded up front.
    const int myq1 = qt1 * 64 + wave * 16 + lrow;
    const int myq2 = qt2 * 64 + wave * 16 + lrow;
    const bf16* qrow1 = Q + ((long)(b * SEQ + myq1)) * (NH * HD) + h * HD;
    const bf16* qrow2 = Q + ((long)(b * SEQ + myq2)) * (NH * HD) + h * HD;
    bf16x8 bqw[4], bq2[4];
#pragma unroll
    for (int ks = 0; ks < 4; ++ks) {
        bqw[ks] = *(const bf16x8*)(qrow1 + ks * 32 + quad * 8);
        bq2[ks] = *(const bf16x8*)(qrow2 + ks * 32 + quad * 8);
    }

    // stage key-block kb into buffer bsel (K 16KB + V 16KB, 8x16B per thread)
    auto stage = [&](int kb, int bsel) {
        const bf16* kg = kfb + (long)kb * 8192 + tid * 8;
        const bf16* vg = vfb + (long)kb * 8192 + tid * 8;
        bf16* kdst = &Kf[bsel][0][0][0] + tid * 8;
        bf16* vdst = &Vf[bsel][0][0][0] + tid * 8;
#pragma unroll
        for (int p = 0; p < 4; ++p) {
            load_lds16(kg + p * 2048, kdst + p * 2048);
            load_lds16(vg + p * 2048, vdst + p * 2048);
        }
    };

    // prologue: stage kb=0 (tile 1) into buffer 0
    stage(0, 0);
    __syncthreads();

    float m_i = -__builtin_inff(), l_i = 0.f;
    f32x4 oT[8] = {};   // out^T: d = dt*16 + quad*4 + r, q = lane&15
    int myq = myq1;

    // epilogue writer (8B stores per dt)
    auto epilogue = [&](int qrow) {
        float inv_l = 1.0f / l_i;
        bf16* obase = O + ((long)(b * SEQ + qrow)) * (NH * HD) + h * HD;
#pragma unroll
        for (int dt = 0; dt < 8; ++dt) {
            bf16x4 o = {(bf16)(oT[dt][0] * inv_l), (bf16)(oT[dt][1] * inv_l),
                        (bf16)(oT[dt][2] * inv_l), (bf16)(oT[dt][3] * inv_l)};
            *(bf16x4*)(obase + dt * 16 + quad * 4) = o;
        }
    };

#pragma unroll 1
    for (int i = 0; i < TOTAL; ++i) {
        const int cur = i & 1;
        // stage next key-block into the other buffer (released at last barrier)
        if (i + 1 < TOTAL) {
            int kbn = (i + 1 < nkb1) ? (i + 1) : (i + 1 - nkb1);
            stage(kbn, cur ^ 1);
        }
        const int kb = (i < nkb1) ? i : i - nkb1;
        const bool diag = (i == nkb1 - 1) || (i == TOTAL - 1);

        // S^T raw scores: key-tile nt covers keys kb*64+nt*16+quad*4+{0..3}, q=lrow
        f32x4 st[4];
        __builtin_amdgcn_s_setprio(1);
#pragma unroll
        for (int nt = 0; nt < 4; ++nt) {
            f32x4 acc = {};
#pragma unroll
            for (int ks = 0; ks < 4; ++ks) {
                bf16x8 ak = *(const bf16x8*)(&Kf[cur][nt][ks][lane * 8]);
                acc = __builtin_amdgcn_mfma_f32_16x16x32_bf16(ak, bqw[ks], acc, 0, 0, 0);
            }
            st[nt] = acc;
        }
        __builtin_amdgcn_s_setprio(0);
        if (diag) {
#pragma unroll
            for (int nt = 0; nt < 4; ++nt) {
                int kp0 = kb * 64 + nt * 16 + quad * 4;
#pragma unroll
                for (int r = 0; r < 4; ++r)
                    if (kp0 + r > myq) st[nt][r] = -__builtin_inff();
            }
        }

        // per-lane online softmax (lane owns one q row; keys spread over quads)
        float mx = st[0][0];
#pragma unroll
        for (int nt = 0; nt < 4; ++nt)
#pragma unroll
            for (int r = 0; r < 4; ++r) mx = fmaxf(mx, st[nt][r]);
        mx = fmaxf(mx, __shfl_xor(mx, 16, 64));
        mx = fmaxf(mx, __shfl_xor(mx, 32, 64));

        // defer-max: only rescale when some row's max grew past THR
        if (!__all(mx - m_i <= THR)) {
            float mnew = fmaxf(m_i, mx);
            float alpha = fast_exp2((m_i - mnew) * scl2);
            l_i *= alpha;
#pragma unroll
            for (int dt = 0; dt < 8; ++dt)
#pragma unroll
                for (int r = 0; r < 4; ++r) oT[dt][r] *= alpha;
            m_i = mnew;
        }
        float rs = 0.f;
#pragma unroll
        for (int nt = 0; nt < 4; ++nt)
#pragma unroll
            for (int r = 0; r < 4; ++r) {
                float p = fast_exp2((st[nt][r] - m_i) * scl2);
                st[nt][r] = p;
                rs += p;
            }
        rs += __shfl_xor(rs, 16, 64);
        rs += __shfl_xor(rs, 32, 64);
        l_i += rs;

        // P fragments (16x16x16 B-operand): B[n=q=lane&15][k=key=quad*4+j]
        bf16x4 pf[4];
#pragma unroll
        for (int nt = 0; nt < 4; ++nt) {
            bf16x4 tt = {(bf16)st[nt][0], (bf16)st[nt][1],
                         (bf16)st[nt][2], (bf16)st[nt][3]};
            pf[nt] = tt;
        }

        // PV: out^T += V^T · P^T, key-steps of 16; A-frag at lane*8B
        __builtin_amdgcn_s_setprio(1);
#pragma unroll
        for (int nt = 0; nt < 4; ++nt)
#pragma unroll
            for (int dt = 0; dt < 8; ++dt) {
                bf16x4 av = *(const bf16x4*)(&Vf[cur][nt][dt][lane * 4]);
                oT[dt] = mfma_16x16x16(av, pf[nt], oT[dt]);
            }
        __builtin_amdgcn_s_setprio(0);

        // seam: finish tile 1, reset softmax state, switch Q fragments
        if (i == nkb1 - 1) {
            epilogue(myq1);
            m_i = -__builtin_inff();
            l_i = 0.f;
#pragma unroll
            for (int dt = 0; dt < 8; ++dt)
#pragma unroll
                for (int r = 0; r < 4; ++r) oT[dt][r] = 0.f;
            myq = myq2;
#pragma unroll
            for (int ks = 0; ks < 4; ++ks) bqw[ks] = bq2[ks];
        }
        __syncthreads();  // release compute buffer; completes staged loads
    }

    epilogue(myq2);
}

// ---------------------------------------------------------------------------
extern "C" void kernel_launch(void* const* d_in, const int* in_sizes, int n_in,
                              void* d_out, int out_size, void* d_ws, size_t ws_size,
                              hipStream_t stream) {
    const float* q_stream  = (const float*)d_in[0];
    const float* kv_stream = (const float*)d_in[1];
    const float* wq  = (const float*)d_in[2];
    const float* wk  = (const float*)d_in[3];
    const float* wv  = (const float*)d_in[4];
    const float* wo  = (const float*)d_in[5];
    const float* qnw = (const float*)d_in[6];
    const float* knw = (const float*)d_in[7];
    float* out = (float*)d_out;

    // workspace (bf16 elems), total 30M elems = 60MB
    bf16* ws   = (bf16*)d_ws;
    bf16* sb   = ws;                        // 8M: stream buf, later attn out
    bf16* wqT  = ws + 8L * 1024 * 1024;     // 4M: wq^T, later wo^T
    bf16* wkvT = wqT + 4L * 1024 * 1024;    // 2M: [wk^T ; wv^T] = [1024][2048]
    bf16* xq   = wkvT + 2L * 1024 * 1024;   // 8M: [4096][2048]
    bf16* xkv  = xq + 8L * 1024 * 1024;     // 4M: [4096][1024] = [K | V]
    bf16* kf   = xkv + 4L * 1024 * 1024;    // 2M: K fragment-major
    bf16* vf   = kf + 2L * 1024 * 1024;     // 2M: V^T fragment-major

    dim3 tb(32, 8);
    cvt_f32_bf16<<<4096, 256, 0, stream>>>(q_stream, sb, 1048576);
    transpose2d<<<dim3(64, 64), tb, 0, stream>>>(wq, wqT, 2048, 2048);
    transpose2d<<<dim3(16, 64), tb, 0, stream>>>(wk, wkvT, 2048, 512);
    transpose2d<<<dim3(16, 64), tb, 0, stream>>>(wv, wkvT + 512L * 2048, 2048, 512);
    gemm_bt<bf16><<<dim3(16, 32), 256, 0, stream>>>(sb, wqT, xq, 4096, 2048, 2048);
    cvt_f32_bf16<<<4096, 256, 0, stream>>>(kv_stream, sb, 1048576);
    transpose2d<<<dim3(64, 64), tb, 0, stream>>>(wo, wqT, 2048, 2048);
    gemm_bt<bf16><<<dim3(8, 32), 256, 0, stream>>>(sb, wkvT, xkv, 4096, 1024, 2048);
    rmsnorm_head<<<(4096 * 16) / 4, 256, 0, stream>>>(xq, qnw, 4096 * 16, 4, 2048);
    rmsnorm_head<<<(4096 * 4) / 4, 256, 0, stream>>>(xkv, knw, 4096 * 4, 2, 1024);
    repack_k<<<dim3(32, 4, 2), 256, 0, stream>>>(xkv, kf);
    repack_v<<<dim3(32, 4, 2), 256, 0, stream>>>(xkv, vf);
    attn_kernel<<<dim3(512), 256, 0, stream>>>(xq, kf, vf, sb);
    gemm_bt<float><<<dim3(16, 32), 256, 0, stream>>>(sb, wqT, out, 4096, 2048, 2048);

    (void)in_sizes; (void)n_in; (void)out_size; (void)ws_size;
}